// Round 1
// baseline (398.365 us; speedup 1.0000x reference)
//
#include <hip/hip_runtime.h>
#include <math.h>

// Problem constants (fixed by setup_inputs):
//   x: (512, 512, 9, 9) fp32, theta: (4,) fp32, lam: (4,) fp32
//   out: (4*512, 512, 9, 9) fp32 = gabor[g,h,w] * x[co,ci,h,w]
#define NG   4
#define HW   81                    // 9*9
#define NELT (512 * 512 * 81)      // elements of x = 21,233,664
#define N4   (NELT / 4)            // float4 count   =  5,308,416
#define BLK  256
#define NBLK (N4 / BLK)            // 20,736 exact

typedef float vf4 __attribute__((ext_vector_type(4)));

__global__ __launch_bounds__(BLK) void gabor_mul_kernel(
    const float* __restrict__ x,
    const float* __restrict__ theta,
    const float* __restrict__ lam,
    float* __restrict__ out)
{
    // Transposed gabor table: gt[p] = {g0(p), g1(p), g2(p), g3(p)}
    // -> one ds_read_b128 per position instead of 4 scalar ds_read_b32,
    //    register-level transpose afterwards is free (component select).
    __shared__ vf4 gt[HW];

    const float PI_F = 3.14159274101257324f;       // np.float32(np.pi)
    const float INV_2SIG2 = 1.0f / (2.0f * PI_F * PI_F);  // sigma = pi
    if (threadIdx.x < HW) {
        int p = threadIdx.x;
        int i = p / 9;
        int j = p - i * 9;
        float fy = (float)(i - 4);
        float fx = (float)(j - 4);
        // env is rotation-invariant: xr^2 + yr^2 = fx^2 + fy^2
        float env = expf(-(fx * fx + fy * fy) * INV_2SIG2);
        vf4 v;
#pragma unroll
        for (int gi = 0; gi < NG; ++gi) {
            float th = theta[gi];
            float l  = lam[gi];
            float xr = fx * cosf(th) + fy * sinf(th);
            v[gi] = env * cosf(2.0f * PI_F * xr * l);
        }
        gt[p] = v;
    }
    __syncthreads();

    // --- One float4 of x per thread; 4 output float4 stores (one per g) ---
    unsigned tid  = blockIdx.x * BLK + threadIdx.x;   // grid is exact: tid < N4
    unsigned base = tid * 4u;
    unsigned p0   = base % 81u;                       // magic-mul, no div unit
    unsigned p1 = p0 + 1u; if (p1 >= 81u) p1 -= 81u;
    unsigned p2 = p1 + 1u; if (p2 >= 81u) p2 -= 81u;
    unsigned p3 = p2 + 1u; if (p3 >= 81u) p3 -= 81u;

    const vf4 xv = ((const vf4*)x)[tid];

    // 4 x ds_read_b128: all 16 gabor coefficients this thread needs.
    vf4 q0 = gt[p0];
    vf4 q1 = gt[p1];
    vf4 q2 = gt[p2];
    vf4 q3 = gt[p3];

    vf4* out4 = (vf4*)out;

    // g = 0..3: select component g of each q (register transpose, free).
    vf4 o0 = { xv.x * q0.x, xv.y * q1.x, xv.z * q2.x, xv.w * q3.x };
    vf4 o1 = { xv.x * q0.y, xv.y * q1.y, xv.z * q2.y, xv.w * q3.y };
    vf4 o2 = { xv.x * q0.z, xv.y * q1.z, xv.z * q2.z, xv.w * q3.z };
    vf4 o3 = { xv.x * q0.w, xv.y * q1.w, xv.z * q2.w, xv.w * q3.w };

    // Non-temporal: out is write-once, never re-read -> don't thrash x
    // (84.9 MB, L3-resident) out of L2/L3 with 339.7 MB of streaming writes.
    __builtin_nontemporal_store(o0, &out4[(size_t)0 * N4 + tid]);
    __builtin_nontemporal_store(o1, &out4[(size_t)1 * N4 + tid]);
    __builtin_nontemporal_store(o2, &out4[(size_t)2 * N4 + tid]);
    __builtin_nontemporal_store(o3, &out4[(size_t)3 * N4 + tid]);
}

extern "C" void kernel_launch(void* const* d_in, const int* in_sizes, int n_in,
                              void* d_out, int out_size, void* d_ws, size_t ws_size,
                              hipStream_t stream) {
    const float* x     = (const float*)d_in[0];
    const float* theta = (const float*)d_in[1];
    const float* lam   = (const float*)d_in[2];
    float* out = (float*)d_out;

    gabor_mul_kernel<<<NBLK, BLK, 0, stream>>>(x, theta, lam, out);
}

// Round 2
// 395.614 us; speedup vs baseline: 1.0070x; 1.0070x over previous
//
#include <hip/hip_runtime.h>
#include <math.h>

// Problem constants (fixed by setup_inputs):
//   x: (512, 512, 9, 9) fp32, theta: (4,) fp32, lam: (4,) fp32
//   out: (4*512, 512, 9, 9) fp32 = gabor[g,h,w] * x[co,ci,h,w]
#define NG   4
#define HW   81                    // 9*9
#define NELT (512 * 512 * 81)      // elements of x = 21,233,664
#define N4   (NELT / 4)            // float4 count   =  5,308,416
#define BLK  256
// Grid-stride: 8 blocks/CU x 256 CUs. Each thread loops ~10.1 times, so the
// per-block gabor-table build (transcendentals + barrier) is amortized ~10x
// vs the previous 20,736-block launch where it was ~half of every block's life.
#define NBLK 2048

typedef float vf4 __attribute__((ext_vector_type(4)));

__global__ __launch_bounds__(BLK) void gabor_mul_kernel(
    const float* __restrict__ x,
    const float* __restrict__ theta,
    const float* __restrict__ lam,
    float* __restrict__ out)
{
    // Transposed gabor table: gt[p] = {g0(p), g1(p), g2(p), g3(p)}
    // -> one ds_read_b128 per position, register transpose afterwards is free.
    __shared__ vf4 gt[HW];

    const float PI_F = 3.14159274101257324f;       // np.float32(np.pi)
    const float INV_2SIG2 = 1.0f / (2.0f * PI_F * PI_F);  // sigma = pi
    if (threadIdx.x < HW) {
        int p = threadIdx.x;
        int i = p / 9;
        int j = p - i * 9;
        float fy = (float)(i - 4);
        float fx = (float)(j - 4);
        // env is rotation-invariant: xr^2 + yr^2 = fx^2 + fy^2
        float env = expf(-(fx * fx + fy * fy) * INV_2SIG2);
        vf4 v;
#pragma unroll
        for (int gi = 0; gi < NG; ++gi) {
            float th = theta[gi];
            float l  = lam[gi];
            float xr = fx * cosf(th) + fy * sinf(th);
            v[gi] = env * cosf(2.0f * PI_F * xr * l);
        }
        gt[p] = v;
    }
    __syncthreads();

    const unsigned stride = NBLK * BLK;               // 524,288 float4 / iter
    vf4* out4 = (vf4*)out;

    for (unsigned tid = blockIdx.x * BLK + threadIdx.x; tid < N4; tid += stride) {
        unsigned base = tid * 4u;
        unsigned p0   = base % 81u;                   // magic-mul, no div unit
        unsigned p1 = p0 + 1u; if (p1 >= 81u) p1 -= 81u;
        unsigned p2 = p1 + 1u; if (p2 >= 81u) p2 -= 81u;
        unsigned p3 = p2 + 1u; if (p3 >= 81u) p3 -= 81u;

        const vf4 xv = ((const vf4*)x)[tid];

        // 4 x ds_read_b128: all 16 gabor coefficients this thread needs.
        vf4 q0 = gt[p0];
        vf4 q1 = gt[p1];
        vf4 q2 = gt[p2];
        vf4 q3 = gt[p3];

        // g = 0..3: select component g of each q (register transpose, free).
        vf4 o0 = { xv.x * q0.x, xv.y * q1.x, xv.z * q2.x, xv.w * q3.x };
        vf4 o1 = { xv.x * q0.y, xv.y * q1.y, xv.z * q2.y, xv.w * q3.y };
        vf4 o2 = { xv.x * q0.z, xv.y * q1.z, xv.z * q2.z, xv.w * q3.z };
        vf4 o3 = { xv.x * q0.w, xv.y * q1.w, xv.z * q2.w, xv.w * q3.w };

        // Non-temporal: out is write-once, never re-read -> don't thrash x
        // (84.9 MB, L3-resident) out of L2/L3 with 339.7 MB of streaming writes.
        __builtin_nontemporal_store(o0, &out4[(size_t)0 * N4 + tid]);
        __builtin_nontemporal_store(o1, &out4[(size_t)1 * N4 + tid]);
        __builtin_nontemporal_store(o2, &out4[(size_t)2 * N4 + tid]);
        __builtin_nontemporal_store(o3, &out4[(size_t)3 * N4 + tid]);
    }
}

extern "C" void kernel_launch(void* const* d_in, const int* in_sizes, int n_in,
                              void* d_out, int out_size, void* d_ws, size_t ws_size,
                              hipStream_t stream) {
    const float* x     = (const float*)d_in[0];
    const float* theta = (const float*)d_in[1];
    const float* lam   = (const float*)d_in[2];
    float* out = (float*)d_out;

    gabor_mul_kernel<<<NBLK, BLK, 0, stream>>>(x, theta, lam, out);
}